// Round 1
// baseline (16481.461 us; speedup 1.0000x reference)
//
#include <hip/hip_runtime.h>
#include <hip/hip_bf16.h>
#include <math.h>

#define B_    2
#define S_    2048
#define M_TOT 4096      // B_*S_
#define DIM_  2048
#define NH_   16
#define QL_   1536
#define KVL_  512
#define QKN_  128
#define QKR_  64
#define VH_   128
#define QKH_  192
#define QSTR  3072      // NH_*QKH_

// ---------------------------------------------------------------------------
// Generic fp32 GEMM:  C[m][n] = sum_k A[m][k]*W[n][k] + bias[n]
// A: M x K row-major, W: N x K row-major. 64x64 tile, BK=16, 256 thr, 4x4/thr.
// Requires M%64==0, N%64==0, K%16==0 (true for all call sites here).
// ---------------------------------------------------------------------------
__global__ __launch_bounds__(256)
void gemm_bias_nt(const float* __restrict__ A, const float* __restrict__ W,
                  const float* __restrict__ bias, float* __restrict__ C,
                  int M, int N, int K)
{
    __shared__ float As[16][68];   // [k][m], pad 68 (17*16B rows, aligned float4)
    __shared__ float Bs[16][68];   // [k][n]
    const int tid = threadIdx.x;
    const int m0 = blockIdx.y * 64;
    const int n0 = blockIdx.x * 64;
    const int tx = tid & 15, ty = tid >> 4;
    const int row = tid >> 2;          // 0..63
    const int kk  = (tid & 3) << 2;    // 0,4,8,12
    float acc[4][4] = {};

    for (int k0 = 0; k0 < K; k0 += 16) {
        float4 av = *(const float4*)(A + (size_t)(m0 + row) * K + k0 + kk);
        float4 bv = *(const float4*)(W + (size_t)(n0 + row) * K + k0 + kk);
        __syncthreads();
        As[kk+0][row] = av.x; As[kk+1][row] = av.y; As[kk+2][row] = av.z; As[kk+3][row] = av.w;
        Bs[kk+0][row] = bv.x; Bs[kk+1][row] = bv.y; Bs[kk+2][row] = bv.z; Bs[kk+3][row] = bv.w;
        __syncthreads();
        #pragma unroll
        for (int k = 0; k < 16; ++k) {
            float4 a4 = *(const float4*)&As[k][ty * 4];
            float4 b4 = *(const float4*)&Bs[k][tx * 4];
            float a[4] = {a4.x, a4.y, a4.z, a4.w};
            float b[4] = {b4.x, b4.y, b4.z, b4.w};
            #pragma unroll
            for (int i = 0; i < 4; ++i)
                #pragma unroll
                for (int j = 0; j < 4; ++j)
                    acc[i][j] += a[i] * b[j];
        }
    }
    #pragma unroll
    for (int i = 0; i < 4; ++i) {
        int m = m0 + ty * 4 + i;
        #pragma unroll
        for (int j = 0; j < 4; ++j) {
            int n = n0 + tx * 4 + j;
            C[(size_t)m * N + n] = acc[i][j] + bias[n];
        }
    }
}

// ---------------------------------------------------------------------------
// In-place RMSNorm over last dim D (one block per row)
// ---------------------------------------------------------------------------
__global__ __launch_bounds__(256)
void rmsnorm_inplace(float* __restrict__ X, const float* __restrict__ w, int D)
{
    const int m = blockIdx.x;
    float* x = X + (size_t)m * D;
    float ss = 0.f;
    for (int k = threadIdx.x; k < D; k += 256) { float v = x[k]; ss += v * v; }
    __shared__ float red[256];
    red[threadIdx.x] = ss;
    __syncthreads();
    for (int s = 128; s > 0; s >>= 1) {
        if (threadIdx.x < s) red[threadIdx.x] += red[threadIdx.x + s];
        __syncthreads();
    }
    const float scale = rsqrtf(red[0] / (float)D + 1e-6f);
    for (int k = threadIdx.x; k < D; k += 256) x[k] = x[k] * scale * w[k];
}

// ---------------------------------------------------------------------------
// kv_a (4096 x 576): rmsnorm first 512 -> KV; rotary on last 64 -> KPE
// ---------------------------------------------------------------------------
__global__ __launch_bounds__(256)
void kv_norm_rope(const float* __restrict__ KVa, const float* __restrict__ w,
                  const float* __restrict__ freqs, float* __restrict__ KV,
                  float* __restrict__ KPE)
{
    const int m = blockIdx.x;
    const int s = m & (S_ - 1);
    const float* x = KVa + (size_t)m * 576;
    float ss = 0.f;
    for (int k = threadIdx.x; k < 512; k += 256) { float v = x[k]; ss += v * v; }
    __shared__ float red[256];
    red[threadIdx.x] = ss;
    __syncthreads();
    for (int st = 128; st > 0; st >>= 1) {
        if (threadIdx.x < st) red[threadIdx.x] += red[threadIdx.x + st];
        __syncthreads();
    }
    const float scale = rsqrtf(red[0] / 512.f + 1e-6f);
    for (int k = threadIdx.x; k < 512; k += 256)
        KV[(size_t)m * 512 + k] = x[k] * scale * w[k];
    if (threadIdx.x < 32) {
        int i = threadIdx.x;
        float c  = freqs[(s * 32 + i) * 2 + 0];
        float sn = freqs[(s * 32 + i) * 2 + 1];
        float x0 = x[512 + 2 * i], x1 = x[512 + 2 * i + 1];
        KPE[(size_t)m * 64 + 2 * i]     = x0 * c - x1 * sn;
        KPE[(size_t)m * 64 + 2 * i + 1] = x1 * c + x0 * sn;
    }
}

// ---------------------------------------------------------------------------
// In-place rotary on q_pe part of q (per m, per head, 32 pairs)
// ---------------------------------------------------------------------------
__global__ __launch_bounds__(256)
void q_rope_inplace(float* __restrict__ Q, const float* __restrict__ freqs)
{
    const int idx = blockIdx.x * 256 + threadIdx.x;  // m*512 + h*32 + i
    const int i = idx & 31;
    const int h = (idx >> 5) & 15;
    const int m = idx >> 9;
    const int s = m & (S_ - 1);
    const float c  = freqs[(s * 32 + i) * 2 + 0];
    const float sn = freqs[(s * 32 + i) * 2 + 1];
    float* p = Q + (size_t)m * QSTR + h * QKH_ + QKN_ + 2 * i;
    const float x0 = p[0], x1 = p[1];
    p[0] = x0 * c - x1 * sn;
    p[1] = x1 * c + x0 * sn;
}

// ---------------------------------------------------------------------------
// Fused MLA attention: per (b, h, 16-row q-tile):
//   prologue: q_abs = q_nope @ wkv_b[h, :128, :]  (into LDS)
//   main: flash over 8-key tiles: scores = q_abs.kv + q_pe.k_pe, causal,
//         online softmax, acc += P @ kv
//   epilogue: OutH = (acc/l) @ wkv_b[h, 128:, :]^T
// ---------------------------------------------------------------------------
#define PADQ 516
#define PADK 516

__global__ __launch_bounds__(256)
void mla_attn(const float* __restrict__ Q, const float* __restrict__ KV,
              const float* __restrict__ KPE, const float* __restrict__ WKVB,
              float* __restrict__ OutH)
{
    __shared__ float s_qabs[16 * PADQ];   // 16 x 512 (padded)
    __shared__ float s_qpe[16 * 68];      // 16 x 64
    __shared__ float s_kv[8 * PADK];      // 8 x 512; prologue union: qn[16*132]+wb[64*17]
    __shared__ float s_kpe[8 * 68];       // 8 x 64
    __shared__ float s_sc[16 * 8];
    __shared__ float s_p[16 * 8];
    __shared__ float s_m[16], s_l[16], s_alpha[16];

    const int tid = threadIdx.x;
    const int qt = blockIdx.x, h = blockIdx.y, b = blockIdx.z;
    const int qs = qt * 16;
    const int m0 = b * S_ + qs;

    // ---- load q_pe tile (already rotated): 16 x 64 ----
    #pragma unroll
    for (int j = 0; j < 4; ++j) {
        int idx = j * 256 + tid;
        int r = idx >> 6, c = idx & 63;
        s_qpe[r * 68 + c] = Q[(size_t)(m0 + r) * QSTR + h * QKH_ + QKN_ + c];
    }

    // ---- prologue: absorb q_nope into latent space ----
    float* qn = s_kv;               // 16 x 132 (uses 2112 of 4128 floats)
    float* wb = s_kv + 16 * 132;    // 64 x 17  (1088; total 3200 <= 4128)
    #pragma unroll
    for (int j = 0; j < 8; ++j) {
        int idx = j * 256 + tid;
        int r = idx >> 7, d = idx & 127;
        qn[r * 132 + d] = Q[(size_t)(m0 + r) * QSTR + h * QKH_ + d];
    }
    const int rr = tid >> 4, cc = tid & 15;
    for (int ch = 0; ch < 32; ++ch) {       // 16-col chunks of the 512 latent dims
        float sum = 0.f;
        for (int dh = 0; dh < 2; ++dh) {    // 64-row subchunks of the 128 nope dims
            __syncthreads();
            #pragma unroll
            for (int j = 0; j < 4; ++j) {
                int idx = j * 256 + tid;
                int d = idx >> 4, c = idx & 15;
                wb[d * 17 + c] = WKVB[(size_t)(h * 256 + dh * 64 + d) * 512 + ch * 16 + c];
            }
            __syncthreads();
            #pragma unroll 8
            for (int d = 0; d < 64; ++d)
                sum += qn[rr * 132 + dh * 64 + d] * wb[d * 17 + cc];
        }
        s_qabs[rr * PADQ + ch * 16 + cc] = sum;
    }

    if (tid < 16) { s_m[tid] = -1e30f; s_l[tid] = 0.f; }
    float acc[8][4];
    #pragma unroll
    for (int j = 0; j < 8; ++j) acc[j][0] = acc[j][1] = acc[j][2] = acc[j][3] = 0.f;

    const float scale = 0.07216878364870323f;   // 1/sqrt(192)
    const int r16 = tid >> 4;
    const int c4  = (tid & 15) * 4;
    const int nkeys = qs + 16;

    for (int kt = 0; kt < nkeys; kt += 8) {
        __syncthreads();   // protect s_kv / s_qabs readers of previous phase
        // load kv tile 8x512 (float4)
        #pragma unroll
        for (int j = 0; j < 4; ++j) {
            int idx = j * 256 + tid;            // 1024 float4 slots
            int t = idx >> 7, c = (idx & 127) << 2;
            *(float4*)&s_kv[t * PADK + c] =
                *(const float4*)&KV[(size_t)(b * S_ + kt + t) * 512 + c];
        }
        // load k_pe tile 8x64
        #pragma unroll
        for (int j = 0; j < 2; ++j) {
            int idx = j * 256 + tid;
            int t = idx >> 6, c = idx & 63;
            s_kpe[t * 68 + c] = KPE[(size_t)(b * S_ + kt + t) * 64 + c];
        }
        __syncthreads();

        // scores: 16 rows x 8 keys, 576-dot each
        if (tid < 128) {
            int r = tid >> 3, t = tid & 7;
            float dot = 0.f;
            #pragma unroll 8
            for (int c = 0; c < 512; c += 4) {
                float4 qa = *(const float4*)&s_qabs[r * PADQ + c];
                float4 kb = *(const float4*)&s_kv[t * PADK + c];
                dot += qa.x * kb.x + qa.y * kb.y + qa.z * kb.z + qa.w * kb.w;
            }
            #pragma unroll
            for (int c = 0; c < 64; c += 4) {
                float4 qa = *(const float4*)&s_qpe[r * 68 + c];
                float4 kb = *(const float4*)&s_kpe[t * 68 + c];
                dot += qa.x * kb.x + qa.y * kb.y + qa.z * kb.z + qa.w * kb.w;
            }
            dot *= scale;
            if (kt + t > qs + r) dot = -1e30f;   // causal mask
            s_sc[r * 8 + t] = dot;
        }
        __syncthreads();

        // online softmax state update (one thread per row)
        if (tid < 16) {
            int r = tid;
            float mx = s_m[r];
            #pragma unroll
            for (int t = 0; t < 8; ++t) mx = fmaxf(mx, s_sc[r * 8 + t]);
            float alpha = expf(s_m[r] - mx);
            float l = s_l[r] * alpha;
            #pragma unroll
            for (int t = 0; t < 8; ++t) {
                float p = expf(s_sc[r * 8 + t] - mx);
                s_p[r * 8 + t] = p;
                l += p;
            }
            s_m[r] = mx; s_l[r] = l; s_alpha[r] = alpha;
        }
        __syncthreads();

        // rescale + PV accumulate: thread (r16, 4-col groups c4 + 64j)
        const float al = s_alpha[r16];
        float pr[8];
        #pragma unroll
        for (int t = 0; t < 8; ++t) pr[t] = s_p[r16 * 8 + t];
        #pragma unroll
        for (int j = 0; j < 8; ++j) {
            int c = c4 + 64 * j;
            float ax = acc[j][0] * al, ay = acc[j][1] * al;
            float az = acc[j][2] * al, aw = acc[j][3] * al;
            #pragma unroll
            for (int t = 0; t < 8; ++t) {
                float p = pr[t];
                float4 kvv = *(const float4*)&s_kv[t * PADK + c];
                ax += p * kvv.x; ay += p * kvv.y; az += p * kvv.z; aw += p * kvv.w;
            }
            acc[j][0] = ax; acc[j][1] = ay; acc[j][2] = az; acc[j][3] = aw;
        }
    }

    // ---- epilogue: normalize, stash in LDS, V-project ----
    __syncthreads();
    const float linv = 1.f / s_l[r16];
    #pragma unroll
    for (int j = 0; j < 8; ++j) {
        int c = c4 + 64 * j;
        s_qabs[r16 * PADQ + c + 0] = acc[j][0] * linv;
        s_qabs[r16 * PADQ + c + 1] = acc[j][1] * linv;
        s_qabs[r16 * PADQ + c + 2] = acc[j][2] * linv;
        s_qabs[r16 * PADQ + c + 3] = acc[j][3] * linv;
    }
    __syncthreads();
    {
        const int r = tid >> 4, d0 = tid & 15;
        for (int j = 0; j < 8; ++j) {
            int d = d0 + 16 * j;
            const float* wv = WKVB + (size_t)(h * 256 + 128 + d) * 512;
            float sum = 0.f;
            #pragma unroll 8
            for (int c = 0; c < 512; c += 4) {
                float4 qa = *(const float4*)&s_qabs[r * PADQ + c];
                sum += qa.x * wv[c] + qa.y * wv[c + 1] + qa.z * wv[c + 2] + qa.w * wv[c + 3];
            }
            OutH[(size_t)(m0 + r) * DIM_ + h * VH_ + d] = sum;
        }
    }
}

// ---------------------------------------------------------------------------
extern "C" void kernel_launch(void* const* d_in, const int* in_sizes, int n_in,
                              void* d_out, int out_size, void* d_ws, size_t ws_size,
                              hipStream_t stream)
{
    (void)in_sizes; (void)n_in; (void)out_size; (void)ws_size;
    // setup_inputs() dict order: x, freqs_cis, mask, start_pos, then params
    const float* x         = (const float*)d_in[0];
    const float* freqs     = (const float*)d_in[1];
    // d_in[2] = mask (causal, handled analytically); d_in[3] = start_pos (0)
    const float* wq_a_w    = (const float*)d_in[4];
    const float* wq_a_b    = (const float*)d_in[5];
    const float* q_norm_w  = (const float*)d_in[6];
    const float* wq_b_w    = (const float*)d_in[7];
    const float* wq_b_b    = (const float*)d_in[8];
    const float* wkv_a_w   = (const float*)d_in[9];
    const float* wkv_a_b   = (const float*)d_in[10];
    const float* kv_norm_w = (const float*)d_in[11];
    const float* wkv_b_w   = (const float*)d_in[12];
    const float* wo_w      = (const float*)d_in[13];
    const float* wo_b      = (const float*)d_in[14];
    float* out = (float*)d_out;

    // workspace layout (floats); total ~128 MB
    float* ws   = (float*)d_ws;
    float* q_a  = ws;                                  // 4096*1536
    float* q    = q_a  + (size_t)M_TOT * QL_;          // 4096*3072
    float* kv_a = q    + (size_t)M_TOT * QSTR;         // 4096*576
    float* kv   = kv_a + (size_t)M_TOT * 576;          // 4096*512
    float* kpe  = kv   + (size_t)M_TOT * KVL_;         // 4096*64
    float* outh = kpe  + (size_t)M_TOT * QKR_;         // 4096*2048

    dim3 blk(256);
    // q path
    gemm_bias_nt<<<dim3(QL_ / 64, M_TOT / 64), blk, 0, stream>>>(
        x, wq_a_w, wq_a_b, q_a, M_TOT, QL_, DIM_);
    rmsnorm_inplace<<<M_TOT, blk, 0, stream>>>(q_a, q_norm_w, QL_);
    gemm_bias_nt<<<dim3(QSTR / 64, M_TOT / 64), blk, 0, stream>>>(
        q_a, wq_b_w, wq_b_b, q, M_TOT, QSTR, QL_);
    q_rope_inplace<<<(M_TOT * NH_ * 32) / 256, blk, 0, stream>>>(q, freqs);
    // kv path
    gemm_bias_nt<<<dim3(576 / 64, M_TOT / 64), blk, 0, stream>>>(
        x, wkv_a_w, wkv_a_b, kv_a, M_TOT, 576, DIM_);
    kv_norm_rope<<<M_TOT, blk, 0, stream>>>(kv_a, kv_norm_w, freqs, kv, kpe);
    // fused absorbed attention
    mla_attn<<<dim3(S_ / 16, NH_, B_), blk, 0, stream>>>(q, kv, kpe, wkv_b_w, outh);
    // output projection
    gemm_bias_nt<<<dim3(DIM_ / 64, M_TOT / 64), blk, 0, stream>>>(
        outh, wo_w, wo_b, out, M_TOT, DIM_, DIM_);
}

// Round 2
// 1879.433 us; speedup vs baseline: 8.7694x; 8.7694x over previous
//
#include <hip/hip_runtime.h>
#include <math.h>

#define B_    2
#define S_    2048
#define M_TOT 4096
#define DIM_  2048
#define NH_   16
#define QL_   1536
#define KVL_  512
#define QKN_  128
#define QKR_  64
#define VH_   128
#define QKH_  192
#define QSTR  3072      // NH_*QKH_
#define QOSTR 9216      // NH_*576 (per-row stride of QO buffer)

typedef short s16x8 __attribute__((ext_vector_type(8)));
typedef float f32x4 __attribute__((ext_vector_type(4)));
typedef unsigned short u16;
#define AS1 __attribute__((address_space(1)))
#define AS3 __attribute__((address_space(3)))

__device__ inline u16 f2bf(float f) {
    unsigned u = __float_as_uint(f);
    unsigned r = u + 0x7FFFu + ((u >> 16) & 1u);   // round-to-nearest-even
    return (u16)(r >> 16);
}
__device__ inline float bf2f(u16 h) { return __uint_as_float(((unsigned)h) << 16); }

// ---------------------------------------------------------------------------
// m97-pattern bf16 MFMA GEMM: C[z][m][n] = alpha * sum_k A[z][m][k]*B[z][n][k] (+bias[n])
// A: bf16 rows ldA; B ("W"): bf16 rows ldB (N x K row-major, i.e. B^T input).
// 128x128 tile, BK=32, 256 thr = 4 waves (2x2 of 64x64), 16x16x32 MFMA, 4x4 acc.
// M % 128 == 0 required. N arbitrary (B-row clamp + store guard). K % 32 == 0.
// causalSkip: skip tile if n0 > m0+127 (scores). causalK: Kend = min(K, m0+128) (PV).
// ---------------------------------------------------------------------------
__global__ __launch_bounds__(256)
void gemm_bf16(const u16* __restrict__ A, const u16* __restrict__ Bm,
               const float* __restrict__ bias, void* __restrict__ Cv,
               int M, int N, int K, int ldA, int ldB, int ldC,
               long long sAz, long long sBz, long long sCz,
               float alpha, int outF32, int causalSkip, int causalK)
{
    __shared__ u16 As[128 * 32];   // row-major 128 x 32 bf16, NO padding (global_load_lds)
    __shared__ u16 Bs[128 * 32];
    const int tid = threadIdx.x;
    const int w = tid >> 6, l = tid & 63;
    const int m0 = blockIdx.y * 128, n0 = blockIdx.x * 128;
    if (causalSkip && n0 > m0 + 127) return;
    const int z = blockIdx.z;
    const u16* Az = A + (size_t)z * sAz;
    const u16* Bz = Bm + (size_t)z * sBz;

    const int rin = l >> 2;          // row within 16-row chunk
    const int cel = (l & 3) * 8;     // bf16 col within 32-wide row (16B granules)
    const int lane15 = l & 15, quad = l >> 4;
    const int wm = w & 1, wn = w >> 1;

    f32x4 acc[4][4] = {};
    const int Kend = causalK ? (K < m0 + 128 ? K : m0 + 128) : K;

    for (int k0 = 0; k0 < Kend; k0 += 32) {
        __syncthreads();
        #pragma unroll
        for (int c = 0; c < 2; ++c) {
            const int chunk = w * 2 + c;
            // A chunk: LDS dest == chunk*1024B + lane*16B  (wave-uniform base + lane*size)
            const int rowA = m0 + chunk * 16 + rin;
            const u16* ga = Az + (size_t)rowA * ldA + k0 + cel;
            u16* la = &As[chunk * 512 + rin * 32 + cel];
            __builtin_amdgcn_global_load_lds((const AS1 unsigned*)ga, (AS3 unsigned*)la, 16, 0, 0);
            int rowB = n0 + chunk * 16 + rin;
            if (rowB > N - 1) rowB = N - 1;          // clamp (results discarded on store)
            const u16* gb = Bz + (size_t)rowB * ldB + k0 + cel;
            u16* lb = &Bs[chunk * 512 + rin * 32 + cel];
            __builtin_amdgcn_global_load_lds((const AS1 unsigned*)gb, (AS3 unsigned*)lb, 16, 0, 0);
        }
        __syncthreads();
        s16x8 af[4], bf[4];
        #pragma unroll
        for (int i = 0; i < 4; ++i)
            af[i] = *(const s16x8*)&As[(wm * 64 + i * 16 + lane15) * 32 + quad * 8];
        #pragma unroll
        for (int i = 0; i < 4; ++i)
            bf[i] = *(const s16x8*)&Bs[(wn * 64 + i * 16 + lane15) * 32 + quad * 8];
        #pragma unroll
        for (int mi = 0; mi < 4; ++mi)
            #pragma unroll
            for (int ni = 0; ni < 4; ++ni)
                acc[mi][ni] = __builtin_amdgcn_mfma_f32_16x16x32_bf16(af[mi], bf[ni], acc[mi][ni], 0, 0, 0);
    }

    // epilogue: C layout col = lane&15, row = quad*4 + reg
    const int cmb = m0 + wm * 64, cnb = n0 + wn * 64;
    if (outF32) {
        float* C = (float*)Cv + (size_t)z * sCz;
        #pragma unroll
        for (int mi = 0; mi < 4; ++mi)
            #pragma unroll
            for (int ni = 0; ni < 4; ++ni) {
                const int nn = cnb + ni * 16 + lane15;
                if (nn < N) {
                    const float bv = bias ? bias[nn] : 0.f;
                    #pragma unroll
                    for (int r = 0; r < 4; ++r) {
                        const int mm = cmb + mi * 16 + quad * 4 + r;
                        C[(size_t)mm * ldC + nn] = acc[mi][ni][r] * alpha + bv;
                    }
                }
            }
    } else {
        u16* C = (u16*)Cv + (size_t)z * sCz;
        #pragma unroll
        for (int mi = 0; mi < 4; ++mi)
            #pragma unroll
            for (int ni = 0; ni < 4; ++ni) {
                const int nn = cnb + ni * 16 + lane15;
                if (nn < N) {
                    const float bv = bias ? bias[nn] : 0.f;
                    #pragma unroll
                    for (int r = 0; r < 4; ++r) {
                        const int mm = cmb + mi * 16 + quad * 4 + r;
                        C[(size_t)mm * ldC + nn] = f2bf(acc[mi][ni][r] * alpha + bv);
                    }
                }
            }
    }
}

// ---------------------------------------------------------------------------
__global__ __launch_bounds__(256)
void cast_f32_bf16(const float* __restrict__ src, u16* __restrict__ dst, int n)
{
    for (int i = blockIdx.x * 256 + threadIdx.x; i < n; i += gridDim.x * 256)
        dst[i] = f2bf(src[i]);
}

// wbnT[h][c][d] = wkv_b[h*256+d][c]   (16 x 512 x 128)
__global__ __launch_bounds__(256)
void prep_wbnT(const float* __restrict__ wkvb, u16* __restrict__ dst)
{
    int i = blockIdx.x * 256 + threadIdx.x;            // < 1048576
    int h = i >> 16, rem = i & 65535, c = rem >> 7, d = rem & 127;
    dst[i] = f2bf(wkvb[(size_t)(h * 256 + d) * 512 + c]);
}

// wbv[h][d][c] = wkv_b[h*256+128+d][c]  (16 x 128 x 512)
__global__ __launch_bounds__(256)
void prep_wbv(const float* __restrict__ wkvb, u16* __restrict__ dst)
{
    int i = blockIdx.x * 256 + threadIdx.x;            // < 1048576
    int h = i >> 16, rem = i & 65535;
    dst[i] = f2bf(wkvb[(size_t)h * 131072 + 65536 + rem]);
}

__global__ __launch_bounds__(256)
void rmsnorm_bf16(u16* __restrict__ X, const float* __restrict__ w, int D)
{
    const int m = blockIdx.x;
    u16* x = X + (size_t)m * D;
    float ss = 0.f;
    for (int k = threadIdx.x; k < D; k += 256) { float v = bf2f(x[k]); ss += v * v; }
    __shared__ float red[256];
    red[threadIdx.x] = ss; __syncthreads();
    for (int s = 128; s > 0; s >>= 1) {
        if (threadIdx.x < s) red[threadIdx.x] += red[threadIdx.x + s];
        __syncthreads();
    }
    const float sc = rsqrtf(red[0] / (float)D + 1e-6f);
    for (int k = threadIdx.x; k < D; k += 256) x[k] = f2bf(bf2f(x[k]) * sc * w[k]);
}

// q (bf16, rows QSTR) -> rotate q_pe, write to QO[..., 512:576]
__global__ __launch_bounds__(256)
void rope_q(const u16* __restrict__ q, const float* __restrict__ freqs, u16* __restrict__ QO)
{
    const int idx = blockIdx.x * 256 + threadIdx.x;    // m*512 + h*32 + i
    const int i = idx & 31, h = (idx >> 5) & 15, m = idx >> 9;
    const int s = m & (S_ - 1);
    const float c = freqs[(s * 32 + i) * 2], sn = freqs[(s * 32 + i) * 2 + 1];
    const u16* src = q + (size_t)m * QSTR + h * QKH_ + QKN_ + 2 * i;
    const float x0 = bf2f(src[0]), x1 = bf2f(src[1]);
    u16* dst = QO + (size_t)m * QOSTR + h * 576 + 512 + 2 * i;
    dst[0] = f2bf(x0 * c - x1 * sn);
    dst[1] = f2bf(x1 * c + x0 * sn);
}

// kv_a (bf16, 576): rmsnorm first 512 + rope last 64 -> Kcat (bf16, 576)
__global__ __launch_bounds__(256)
void kv_norm_rope(const u16* __restrict__ kva, const float* __restrict__ w,
                  const float* __restrict__ freqs, u16* __restrict__ Kcat)
{
    const int m = blockIdx.x, s = m & (S_ - 1);
    const u16* x = kva + (size_t)m * 576;
    float ss = 0.f;
    for (int k = threadIdx.x; k < 512; k += 256) { float v = bf2f(x[k]); ss += v * v; }
    __shared__ float red[256];
    red[threadIdx.x] = ss; __syncthreads();
    for (int st = 128; st > 0; st >>= 1) {
        if (threadIdx.x < st) red[threadIdx.x] += red[threadIdx.x + st];
        __syncthreads();
    }
    const float sc = rsqrtf(red[0] / 512.f + 1e-6f);
    for (int k = threadIdx.x; k < 512; k += 256)
        Kcat[(size_t)m * 576 + k] = f2bf(bf2f(x[k]) * sc * w[k]);
    if (threadIdx.x < 32) {
        const int i = threadIdx.x;
        const float c = freqs[(s * 32 + i) * 2], sn = freqs[(s * 32 + i) * 2 + 1];
        const float x0 = bf2f(x[512 + 2 * i]), x1 = bf2f(x[512 + 2 * i + 1]);
        Kcat[(size_t)m * 576 + 512 + 2 * i]     = f2bf(x0 * c - x1 * sn);
        Kcat[(size_t)m * 576 + 512 + 2 * i + 1] = f2bf(x1 * c + x0 * sn);
    }
}

// KVT[b][c][s] = Kcat[b*S+s][c], c < 512 — tiled transpose
__global__ __launch_bounds__(256)
void transpose_kv(const u16* __restrict__ Kcat, u16* __restrict__ KVT)
{
    __shared__ u16 t[64][65];
    const int s0 = blockIdx.x * 64, c0 = blockIdx.y * 64, b = blockIdx.z;
    #pragma unroll
    for (int i = 0; i < 16; ++i) {
        int id = i * 256 + threadIdx.x, r = id >> 6, c = id & 63;
        t[r][c] = Kcat[(size_t)(b * S_ + s0 + r) * 576 + c0 + c];
    }
    __syncthreads();
    #pragma unroll
    for (int i = 0; i < 16; ++i) {
        int id = i * 256 + threadIdx.x, r = id >> 6, c = id & 63;
        KVT[(size_t)(b * 512 + c0 + r) * S_ + s0 + c] = t[c][r];
    }
}

// row-wise causal softmax: S fp32 (z,q,2048) -> P bf16 (zeros beyond q)
__global__ __launch_bounds__(256)
void softmax_causal(const float* __restrict__ S, u16* __restrict__ P)
{
    const int q = blockIdx.x, z = blockIdx.y;
    const float* s = S + (size_t)z * S_ * S_ + (size_t)q * S_;
    u16* p = P + (size_t)z * S_ * S_ + (size_t)q * S_;
    const int n = q + 1;
    __shared__ float red[256];
    float mx = -1e30f;
    for (int c = threadIdx.x; c < n; c += 256) mx = fmaxf(mx, s[c]);
    red[threadIdx.x] = mx; __syncthreads();
    for (int st = 128; st > 0; st >>= 1) {
        if (threadIdx.x < st) red[threadIdx.x] = fmaxf(red[threadIdx.x], red[threadIdx.x + st]);
        __syncthreads();
    }
    const float M = red[0]; __syncthreads();
    float sum = 0.f;
    for (int c = threadIdx.x; c < n; c += 256) sum += expf(s[c] - M);
    red[threadIdx.x] = sum; __syncthreads();
    for (int st = 128; st > 0; st >>= 1) {
        if (threadIdx.x < st) red[threadIdx.x] += red[threadIdx.x + st];
        __syncthreads();
    }
    const float inv = 1.f / red[0];
    for (int c = threadIdx.x; c < S_; c += 256)
        p[c] = (c < n) ? f2bf(expf(s[c] - M) * inv) : (u16)0;
}

// ---------------------------------------------------------------------------
extern "C" void kernel_launch(void* const* d_in, const int* in_sizes, int n_in,
                              void* d_out, int out_size, void* d_ws, size_t ws_size,
                              hipStream_t stream)
{
    (void)in_sizes; (void)n_in; (void)out_size;
    const float* x         = (const float*)d_in[0];
    const float* freqs     = (const float*)d_in[1];
    const float* wq_a_w    = (const float*)d_in[4];
    const float* wq_a_b    = (const float*)d_in[5];
    const float* q_norm_w  = (const float*)d_in[6];
    const float* wq_b_w    = (const float*)d_in[7];
    const float* wq_b_b    = (const float*)d_in[8];
    const float* wkv_a_w   = (const float*)d_in[9];
    const float* wkv_a_b   = (const float*)d_in[10];
    const float* kv_norm_w = (const float*)d_in[11];
    const float* wkv_b_w   = (const float*)d_in[12];
    const float* wo_w      = (const float*)d_in[13];
    const float* wo_b      = (const float*)d_in[14];
    float* out = (float*)d_out;

    char* W = (char*)d_ws;
    u16* x_bf  = (u16*)(W + 0);
    u16* wqa   = (u16*)(W + 16777216);
    u16* wqb   = (u16*)(W + 23068672);
    u16* wkva  = (u16*)(W + 32505856);
    u16* wobf  = (u16*)(W + 34865152);
    u16* wbnT  = (u16*)(W + 43253760);
    u16* wbv   = (u16*)(W + 45350912);
    u16* q_a   = (u16*)(W + 47448064);
    u16* q     = (u16*)(W + 60030976);
    u16* kv_a  = (u16*)(W + 85196800);
    u16* Kcat  = (u16*)(W + 89915392);
    u16* KVT   = (u16*)(W + 94633984);
    u16* QO    = (u16*)(W + 98828288);   // (B*S, NH, 576): q_abs|q_pe, then attn-out
    u16* outh  = (u16*)(W + 174325760);
    const size_t base = 191102976ull;

    int G = 1;                            // heads per score/P group (ws-dependent, constant)
    if (ws_size >= base + 4ull * 25165824ull)      G = 4;
    else if (ws_size >= base + 2ull * 25165824ull) G = 2;
    float* Sbuf = (float*)(W + base);
    u16*   Pbuf = (u16*)(W + base + (size_t)G * 16777216ull);

    const dim3 blk(256);
    const float scale = 0.07216878364870323f;   // 1/sqrt(192)

    // --- dtype prep ---
    cast_f32_bf16<<<2048, blk, 0, stream>>>(x, x_bf, M_TOT * DIM_);
    cast_f32_bf16<<<2048, blk, 0, stream>>>(wq_a_w, wqa, QL_ * DIM_);
    cast_f32_bf16<<<2048, blk, 0, stream>>>(wq_b_w, wqb, QSTR * QL_);
    cast_f32_bf16<<<2048, blk, 0, stream>>>(wkv_a_w, wkva, 576 * DIM_);
    cast_f32_bf16<<<2048, blk, 0, stream>>>(wo_w, wobf, DIM_ * DIM_);
    prep_wbnT<<<4096, blk, 0, stream>>>(wkv_b_w, wbnT);
    prep_wbv<<<4096, blk, 0, stream>>>(wkv_b_w, wbv);

    // --- q path ---
    gemm_bf16<<<dim3(12, 32, 1), blk, 0, stream>>>(x_bf, wqa, wq_a_b, q_a,
        M_TOT, QL_, DIM_, DIM_, DIM_, QL_, 0, 0, 0, 1.f, 0, 0, 0);
    rmsnorm_bf16<<<M_TOT, blk, 0, stream>>>(q_a, q_norm_w, QL_);
    gemm_bf16<<<dim3(24, 32, 1), blk, 0, stream>>>(q_a, wqb, wq_b_b, q,
        M_TOT, QSTR, QL_, QL_, QL_, QSTR, 0, 0, 0, 1.f, 0, 0, 0);
    rope_q<<<(M_TOT * NH_ * 32) / 256, blk, 0, stream>>>(q, freqs, QO);

    // --- kv path ---
    gemm_bf16<<<dim3(5, 32, 1), blk, 0, stream>>>(x_bf, wkva, wkv_a_b, kv_a,
        M_TOT, 576, DIM_, DIM_, DIM_, 576, 0, 0, 0, 1.f, 0, 0, 0);
    kv_norm_rope<<<M_TOT, blk, 0, stream>>>(kv_a, kv_norm_w, freqs, Kcat);
    transpose_kv<<<dim3(32, 8, 2), blk, 0, stream>>>(Kcat, KVT);

    // --- q absorb: QO[..., h, 0:512] = q_nope @ wkv_b[h,:128,:] ---
    gemm_bf16<<<dim3(4, 32, 16), blk, 0, stream>>>(q, wbnT, nullptr, QO,
        M_TOT, 512, 128, QSTR, 128, QOSTR, QKH_, 65536, 576, 1.f, 0, 0, 0);

    // --- attention: per (b, G-head group): scores -> softmax -> PV ---
    for (int b = 0; b < B_; ++b) {
        for (int hs = 0; hs < NH_; hs += G) {
            const u16* Qg = QO + (size_t)b * S_ * QOSTR + hs * 576;
            gemm_bf16<<<dim3(16, 16, G), blk, 0, stream>>>(
                Qg, Kcat + (size_t)b * S_ * 576, nullptr, Sbuf,
                S_, S_, 576, QOSTR, 576, S_, 576, 0, (long long)S_ * S_,
                scale, 1, 1, 0);
            softmax_causal<<<dim3(S_, G), blk, 0, stream>>>(Sbuf, Pbuf);
            gemm_bf16<<<dim3(4, 16, G), blk, 0, stream>>>(
                Pbuf, KVT + (size_t)b * 512 * S_, nullptr, (void*)Qg,
                S_, 512, S_, S_, S_, QOSTR, (long long)S_ * S_, 0, 576,
                1.f, 0, 0, 1);
        }
    }

    // --- V projection: outh[m, h*128+d] = O[m,h,:] . wbv[h,d,:] ---
    gemm_bf16<<<dim3(1, 32, 16), blk, 0, stream>>>(QO, wbv, nullptr, outh,
        M_TOT, VH_, 512, QOSTR, 512, DIM_, 576, 65536, VH_, 1.f, 0, 0, 0);

    // --- output projection (fp32 out) ---
    gemm_bf16<<<dim3(16, 32, 1), blk, 0, stream>>>(outh, wobf, wo_b, out,
        M_TOT, DIM_, DIM_, DIM_, DIM_, DIM_, 0, 0, 0, 1.f, 1, 0, 0);
}

// Round 3
// 1466.380 us; speedup vs baseline: 11.2396x; 1.2817x over previous
//
#include <hip/hip_runtime.h>
#include <math.h>

#define B_    2
#define S_    2048
#define M_TOT 4096
#define DIM_  2048
#define NH_   16
#define QL_   1536
#define KVL_  512
#define QKN_  128
#define QKR_  64
#define VH_   128
#define QKH_  192
#define QSTR  3072      // NH_*QKH_
#define QOSTR 9216      // NH_*576 (per-row stride of QO buffer)

typedef short s16x8 __attribute__((ext_vector_type(8)));
typedef float f32x4 __attribute__((ext_vector_type(4)));
typedef unsigned short u16;
#define AS1 __attribute__((address_space(1)))
#define AS3 __attribute__((address_space(3)))

__device__ inline u16 f2bf(float f) {
    unsigned u = __float_as_uint(f);
    unsigned r = u + 0x7FFFu + ((u >> 16) & 1u);   // round-to-nearest-even
    return (u16)(r >> 16);
}
__device__ inline float bf2f(u16 h) { return __uint_as_float(((unsigned)h) << 16); }

// ---------------------------------------------------------------------------
// m97-pattern bf16 MFMA GEMM (unchanged from round 2 — known good).
// ---------------------------------------------------------------------------
__global__ __launch_bounds__(256)
void gemm_bf16(const u16* __restrict__ A, const u16* __restrict__ Bm,
               const float* __restrict__ bias, void* __restrict__ Cv,
               int M, int N, int K, int ldA, int ldB, int ldC,
               long long sAz, long long sBz, long long sCz,
               float alpha, int outF32)
{
    __shared__ u16 As[128 * 32];
    __shared__ u16 Bs[128 * 32];
    const int tid = threadIdx.x;
    const int w = tid >> 6, l = tid & 63;
    const int m0 = blockIdx.y * 128, n0 = blockIdx.x * 128;
    const int z = blockIdx.z;
    const u16* Az = A + (size_t)z * sAz;
    const u16* Bz = Bm + (size_t)z * sBz;

    const int rin = l >> 2;
    const int cel = (l & 3) * 8;
    const int lane15 = l & 15, quad = l >> 4;
    const int wm = w & 1, wn = w >> 1;

    f32x4 acc[4][4] = {};

    for (int k0 = 0; k0 < K; k0 += 32) {
        __syncthreads();
        #pragma unroll
        for (int c = 0; c < 2; ++c) {
            const int chunk = w * 2 + c;
            const int rowA = m0 + chunk * 16 + rin;
            const u16* ga = Az + (size_t)rowA * ldA + k0 + cel;
            u16* la = &As[chunk * 512 + rin * 32 + cel];
            __builtin_amdgcn_global_load_lds((const AS1 unsigned*)ga, (AS3 unsigned*)la, 16, 0, 0);
            int rowB = n0 + chunk * 16 + rin;
            if (rowB > N - 1) rowB = N - 1;
            const u16* gb = Bz + (size_t)rowB * ldB + k0 + cel;
            u16* lb = &Bs[chunk * 512 + rin * 32 + cel];
            __builtin_amdgcn_global_load_lds((const AS1 unsigned*)gb, (AS3 unsigned*)lb, 16, 0, 0);
        }
        __syncthreads();
        s16x8 af[4], bf[4];
        #pragma unroll
        for (int i = 0; i < 4; ++i)
            af[i] = *(const s16x8*)&As[(wm * 64 + i * 16 + lane15) * 32 + quad * 8];
        #pragma unroll
        for (int i = 0; i < 4; ++i)
            bf[i] = *(const s16x8*)&Bs[(wn * 64 + i * 16 + lane15) * 32 + quad * 8];
        #pragma unroll
        for (int mi = 0; mi < 4; ++mi)
            #pragma unroll
            for (int ni = 0; ni < 4; ++ni)
                acc[mi][ni] = __builtin_amdgcn_mfma_f32_16x16x32_bf16(af[mi], bf[ni], acc[mi][ni], 0, 0, 0);
    }

    const int cmb = m0 + wm * 64, cnb = n0 + wn * 64;
    if (outF32) {
        float* C = (float*)Cv + (size_t)z * sCz;
        #pragma unroll
        for (int mi = 0; mi < 4; ++mi)
            #pragma unroll
            for (int ni = 0; ni < 4; ++ni) {
                const int nn = cnb + ni * 16 + lane15;
                if (nn < N) {
                    const float bv = bias ? bias[nn] : 0.f;
                    #pragma unroll
                    for (int r = 0; r < 4; ++r) {
                        const int mm = cmb + mi * 16 + quad * 4 + r;
                        C[(size_t)mm * ldC + nn] = acc[mi][ni][r] * alpha + bv;
                    }
                }
            }
    } else {
        u16* C = (u16*)Cv + (size_t)z * sCz;
        #pragma unroll
        for (int mi = 0; mi < 4; ++mi)
            #pragma unroll
            for (int ni = 0; ni < 4; ++ni) {
                const int nn = cnb + ni * 16 + lane15;
                if (nn < N) {
                    const float bv = bias ? bias[nn] : 0.f;
                    #pragma unroll
                    for (int r = 0; r < 4; ++r) {
                        const int mm = cmb + mi * 16 + quad * 4 + r;
                        C[(size_t)mm * ldC + nn] = f2bf(acc[mi][ni][r] * alpha + bv);
                    }
                }
            }
    }
}

// ---------------------------------------------------------------------------
// Fused MFMA flash attention.
// Block = 256 thr (4 waves) handles (b, h, 64 q-rows). K-tiles of 128 keys.
// Score phase: each wave computes S[64 x 32-col slice] via 16x16x32 MFMA,
//   streaming Q(64x32)/K(128x32) chunks via global_load_lds (18 chunks, K=576).
// Online softmax in regs + LDS cross-wave reduction. P -> LDS (bf16, pad 136).
// PV phase: O[64x512] += P(64x128) @ KV(128x512), V staged from KVT (B-operand
//   layout = KVT rows), 4 t-chunks of 32. O in registers (C-layout).
// Epilogue: O/l -> bf16, overwrite QO[..., h, 0:512] (block-local rows only).
// LDS: 32KB union(Vs | Ks+Qs) + 17KB Ps + 2KB softmax = ~51KB.
// ---------------------------------------------------------------------------
__global__ __launch_bounds__(256, 2)
void mla_flash(u16* __restrict__ QO, const u16* __restrict__ Kcat,
               const u16* __restrict__ KVT)
{
    __shared__ u16 sA[16384];        // Vs(512x32) | [Ks(128x32) @0, Qs(64x32) @4096]
    __shared__ u16 sP[64 * 136];     // P tile, padded stride 136
    __shared__ float sM[64], sL[64], sAl[64], sMn[64];
    __shared__ float sR[256];        // per-wave row partials [row][w]

    u16* Ks = sA;
    u16* Qs = sA + 4096;
    u16* Vs = sA;

    const int tid = threadIdx.x;
    const int w = tid >> 6, l = tid & 63;
    const int lane15 = l & 15, quad = l >> 4;
    const int qt = 31 - blockIdx.x;            // heavy q-tiles first
    const int h = blockIdx.y, b = blockIdx.z;
    const int qs = qt * 64;
    const size_t qrow0 = (size_t)(b * S_ + qs) * QOSTR + (size_t)h * 576;
    const float scale = 0.07216878364870323f;  // 1/sqrt(192)

    const int rQ = tid >> 2;                   // 0..63
    const int c8 = (tid & 3) * 8;

    f32x4 Oacc[4][8] = {};                     // [mi rows][ci: wave's 128 cols /16]
    if (tid < 64) { sM[tid] = -1e30f; sL[tid] = 0.f; }

    const int ktiles = qt / 2 + 1;
    for (int kt0 = 0; kt0 < ktiles; ++kt0) {
        const int kt = kt0 * 128;
        f32x4 Sacc[4][2] = {};

        // ---- score: S(64x128) = Q(64x576) . K(128x576)^T ----
        for (int k0 = 0; k0 < 576; k0 += 32) {
            __syncthreads();
            {
                const u16* g = QO + qrow0 + (size_t)rQ * QOSTR + k0 + c8;
                u16* ld = &Qs[rQ * 32 + c8];
                __builtin_amdgcn_global_load_lds((const AS1 unsigned*)g, (AS3 unsigned*)ld, 16, 0, 0);
            }
            #pragma unroll
            for (int j = 0; j < 2; ++j) {
                const int row = j * 64 + rQ;
                const u16* g = Kcat + (size_t)(b * S_ + kt + row) * 576 + k0 + c8;
                u16* ld = &Ks[row * 32 + c8];
                __builtin_amdgcn_global_load_lds((const AS1 unsigned*)g, (AS3 unsigned*)ld, 16, 0, 0);
            }
            __syncthreads();
            s16x8 af[4], bf[2];
            #pragma unroll
            for (int mi = 0; mi < 4; ++mi)
                af[mi] = *(const s16x8*)&Qs[(mi * 16 + lane15) * 32 + quad * 8];
            #pragma unroll
            for (int ni = 0; ni < 2; ++ni)
                bf[ni] = *(const s16x8*)&Ks[(w * 32 + ni * 16 + lane15) * 32 + quad * 8];
            #pragma unroll
            for (int mi = 0; mi < 4; ++mi)
                #pragma unroll
                for (int ni = 0; ni < 2; ++ni)
                    Sacc[mi][ni] = __builtin_amdgcn_mfma_f32_16x16x32_bf16(af[mi], bf[ni], Sacc[mi][ni], 0, 0, 0);
        }

        // ---- scale + causal mask + wave-local row max ----
        #pragma unroll
        for (int mi = 0; mi < 4; ++mi)
            #pragma unroll
            for (int r = 0; r < 4; ++r) {
                const int rowg = qs + mi * 16 + quad * 4 + r;
                float mx = -1e30f;
                #pragma unroll
                for (int ni = 0; ni < 2; ++ni) {
                    const int colg = kt + w * 32 + ni * 16 + lane15;
                    float v = Sacc[mi][ni][r] * scale;
                    v = (colg <= rowg) ? v : -1e30f;
                    Sacc[mi][ni][r] = v;
                    mx = fmaxf(mx, v);
                }
                #pragma unroll
                for (int sh = 1; sh < 16; sh <<= 1) mx = fmaxf(mx, __shfl_xor(mx, sh));
                if (lane15 == 0) sR[(mi * 16 + quad * 4 + r) * 4 + w] = mx;
            }
        __syncthreads();
        if (tid < 64) {
            const float m_old = sM[tid];
            float mn = m_old;
            #pragma unroll
            for (int ww = 0; ww < 4; ++ww) mn = fmaxf(mn, sR[tid * 4 + ww]);
            sMn[tid] = mn;
            sAl[tid] = expf(m_old - mn);
            sM[tid] = mn;
        }
        __syncthreads();

        // ---- P = exp(S - m), store to LDS; rescale O; row sums ----
        #pragma unroll
        for (int mi = 0; mi < 4; ++mi)
            #pragma unroll
            for (int r = 0; r < 4; ++r) {
                const int rowl = mi * 16 + quad * 4 + r;
                const float mn = sMn[rowl];
                const float al = sAl[rowl];
                float sum = 0.f;
                #pragma unroll
                for (int ni = 0; ni < 2; ++ni) {
                    const float p = expf(Sacc[mi][ni][r] - mn);
                    sum += p;
                    sP[rowl * 136 + w * 32 + ni * 16 + lane15] = f2bf(p);
                }
                #pragma unroll
                for (int ci = 0; ci < 8; ++ci) Oacc[mi][ci][r] *= al;
                #pragma unroll
                for (int sh = 1; sh < 16; sh <<= 1) sum += __shfl_xor(sum, sh);
                if (lane15 == 0) sR[rowl * 4 + w] = sum;
            }
        __syncthreads();
        if (tid < 64) {
            float s = 0.f;
            #pragma unroll
            for (int ww = 0; ww < 4; ++ww) s += sR[tid * 4 + ww];
            sL[tid] = sL[tid] * sAl[tid] + s;
        }

        // ---- PV: O(64x512) += P(64x128) . KV(128x512), via KVT B-operand ----
        #pragma unroll
        for (int tc = 0; tc < 4; ++tc) {
            __syncthreads();
            #pragma unroll
            for (int j = 0; j < 8; ++j) {
                const int idx = j * 256 + tid;
                const int c = idx >> 2, t8 = (idx & 3) * 8;
                const u16* g = KVT + (size_t)(b * 512 + c) * S_ + kt + tc * 32 + t8;
                u16* ld = &Vs[c * 32 + t8];
                __builtin_amdgcn_global_load_lds((const AS1 unsigned*)g, (AS3 unsigned*)ld, 16, 0, 0);
            }
            __syncthreads();
            s16x8 pf[4];
            #pragma unroll
            for (int mi = 0; mi < 4; ++mi)
                pf[mi] = *(const s16x8*)&sP[(mi * 16 + lane15) * 136 + tc * 32 + quad * 8];
            #pragma unroll
            for (int ci = 0; ci < 8; ++ci) {
                const s16x8 vf = *(const s16x8*)&Vs[(w * 128 + ci * 16 + lane15) * 32 + quad * 8];
                #pragma unroll
                for (int mi = 0; mi < 4; ++mi)
                    Oacc[mi][ci] = __builtin_amdgcn_mfma_f32_16x16x32_bf16(pf[mi], vf, Oacc[mi][ci], 0, 0, 0);
            }
        }
    }

    // ---- epilogue: O/l -> bf16, overwrite QO q_abs region ----
    __syncthreads();
    #pragma unroll
    for (int mi = 0; mi < 4; ++mi)
        #pragma unroll
        for (int r = 0; r < 4; ++r) {
            const int rowl = mi * 16 + quad * 4 + r;
            const float inv = 1.f / sL[rowl];
            #pragma unroll
            for (int ci = 0; ci < 8; ++ci)
                QO[qrow0 + (size_t)rowl * QOSTR + w * 128 + ci * 16 + lane15] =
                    f2bf(Oacc[mi][ci][r] * inv);
        }
}

// ---------------------------------------------------------------------------
__global__ __launch_bounds__(256)
void cast_f32_bf16(const float* __restrict__ src, u16* __restrict__ dst, int n)
{
    for (int i = blockIdx.x * 256 + threadIdx.x; i < n; i += gridDim.x * 256)
        dst[i] = f2bf(src[i]);
}

__global__ __launch_bounds__(256)
void prep_wbnT(const float* __restrict__ wkvb, u16* __restrict__ dst)
{
    int i = blockIdx.x * 256 + threadIdx.x;
    int h = i >> 16, rem = i & 65535, c = rem >> 7, d = rem & 127;
    dst[i] = f2bf(wkvb[(size_t)(h * 256 + d) * 512 + c]);
}

__global__ __launch_bounds__(256)
void prep_wbv(const float* __restrict__ wkvb, u16* __restrict__ dst)
{
    int i = blockIdx.x * 256 + threadIdx.x;
    int h = i >> 16, rem = i & 65535;
    dst[i] = f2bf(wkvb[(size_t)h * 131072 + 65536 + rem]);
}

__global__ __launch_bounds__(256)
void rmsnorm_bf16(u16* __restrict__ X, const float* __restrict__ w, int D)
{
    const int m = blockIdx.x;
    u16* x = X + (size_t)m * D;
    float ss = 0.f;
    for (int k = threadIdx.x; k < D; k += 256) { float v = bf2f(x[k]); ss += v * v; }
    __shared__ float red[256];
    red[threadIdx.x] = ss; __syncthreads();
    for (int s = 128; s > 0; s >>= 1) {
        if (threadIdx.x < s) red[threadIdx.x] += red[threadIdx.x + s];
        __syncthreads();
    }
    const float sc = rsqrtf(red[0] / (float)D + 1e-6f);
    for (int k = threadIdx.x; k < D; k += 256) x[k] = f2bf(bf2f(x[k]) * sc * w[k]);
}

__global__ __launch_bounds__(256)
void rope_q(const u16* __restrict__ q, const float* __restrict__ freqs, u16* __restrict__ QO)
{
    const int idx = blockIdx.x * 256 + threadIdx.x;
    const int i = idx & 31, h = (idx >> 5) & 15, m = idx >> 9;
    const int s = m & (S_ - 1);
    const float c = freqs[(s * 32 + i) * 2], sn = freqs[(s * 32 + i) * 2 + 1];
    const u16* src = q + (size_t)m * QSTR + h * QKH_ + QKN_ + 2 * i;
    const float x0 = bf2f(src[0]), x1 = bf2f(src[1]);
    u16* dst = QO + (size_t)m * QOSTR + h * 576 + 512 + 2 * i;
    dst[0] = f2bf(x0 * c - x1 * sn);
    dst[1] = f2bf(x1 * c + x0 * sn);
}

__global__ __launch_bounds__(256)
void kv_norm_rope(const u16* __restrict__ kva, const float* __restrict__ w,
                  const float* __restrict__ freqs, u16* __restrict__ Kcat)
{
    const int m = blockIdx.x, s = m & (S_ - 1);
    const u16* x = kva + (size_t)m * 576;
    float ss = 0.f;
    for (int k = threadIdx.x; k < 512; k += 256) { float v = bf2f(x[k]); ss += v * v; }
    __shared__ float red[256];
    red[threadIdx.x] = ss; __syncthreads();
    for (int st = 128; st > 0; st >>= 1) {
        if (threadIdx.x < st) red[threadIdx.x] += red[threadIdx.x + st];
        __syncthreads();
    }
    const float sc = rsqrtf(red[0] / 512.f + 1e-6f);
    for (int k = threadIdx.x; k < 512; k += 256)
        Kcat[(size_t)m * 576 + k] = f2bf(bf2f(x[k]) * sc * w[k]);
    if (threadIdx.x < 32) {
        const int i = threadIdx.x;
        const float c = freqs[(s * 32 + i) * 2], sn = freqs[(s * 32 + i) * 2 + 1];
        const float x0 = bf2f(x[512 + 2 * i]), x1 = bf2f(x[512 + 2 * i + 1]);
        Kcat[(size_t)m * 576 + 512 + 2 * i]     = f2bf(x0 * c - x1 * sn);
        Kcat[(size_t)m * 576 + 512 + 2 * i + 1] = f2bf(x1 * c + x0 * sn);
    }
}

__global__ __launch_bounds__(256)
void transpose_kv(const u16* __restrict__ Kcat, u16* __restrict__ KVT)
{
    __shared__ u16 t[64][65];
    const int s0 = blockIdx.x * 64, c0 = blockIdx.y * 64, b = blockIdx.z;
    #pragma unroll
    for (int i = 0; i < 16; ++i) {
        int id = i * 256 + threadIdx.x, r = id >> 6, c = id & 63;
        t[r][c] = Kcat[(size_t)(b * S_ + s0 + r) * 576 + c0 + c];
    }
    __syncthreads();
    #pragma unroll
    for (int i = 0; i < 16; ++i) {
        int id = i * 256 + threadIdx.x, r = id >> 6, c = id & 63;
        KVT[(size_t)(b * 512 + c0 + r) * S_ + s0 + c] = t[c][r];
    }
}

// ---------------------------------------------------------------------------
extern "C" void kernel_launch(void* const* d_in, const int* in_sizes, int n_in,
                              void* d_out, int out_size, void* d_ws, size_t ws_size,
                              hipStream_t stream)
{
    (void)in_sizes; (void)n_in; (void)out_size; (void)ws_size;
    const float* x         = (const float*)d_in[0];
    const float* freqs     = (const float*)d_in[1];
    const float* wq_a_w    = (const float*)d_in[4];
    const float* wq_a_b    = (const float*)d_in[5];
    const float* q_norm_w  = (const float*)d_in[6];
    const float* wq_b_w    = (const float*)d_in[7];
    const float* wq_b_b    = (const float*)d_in[8];
    const float* wkv_a_w   = (const float*)d_in[9];
    const float* wkv_a_b   = (const float*)d_in[10];
    const float* kv_norm_w = (const float*)d_in[11];
    const float* wkv_b_w   = (const float*)d_in[12];
    const float* wo_w      = (const float*)d_in[13];
    const float* wo_b      = (const float*)d_in[14];
    float* out = (float*)d_out;

    char* W = (char*)d_ws;
    u16* x_bf  = (u16*)(W + 0);
    u16* wqa   = (u16*)(W + 16777216);
    u16* wqb   = (u16*)(W + 23068672);
    u16* wkva  = (u16*)(W + 32505856);
    u16* wobf  = (u16*)(W + 34865152);
    u16* wbnT  = (u16*)(W + 43253760);
    u16* wbv   = (u16*)(W + 45350912);
    u16* q_a   = (u16*)(W + 47448064);
    u16* q     = (u16*)(W + 60030976);
    u16* kv_a  = (u16*)(W + 85196800);
    u16* Kcat  = (u16*)(W + 89915392);
    u16* KVT   = (u16*)(W + 94633984);
    u16* QO    = (u16*)(W + 98828288);   // (B*S, NH, 576): q_abs|q_pe -> attn-out
    u16* outh  = (u16*)(W + 174325760);

    const dim3 blk(256);

    // --- dtype prep ---
    cast_f32_bf16<<<2048, blk, 0, stream>>>(x, x_bf, M_TOT * DIM_);
    cast_f32_bf16<<<2048, blk, 0, stream>>>(wq_a_w, wqa, QL_ * DIM_);
    cast_f32_bf16<<<2048, blk, 0, stream>>>(wq_b_w, wqb, QSTR * QL_);
    cast_f32_bf16<<<2048, blk, 0, stream>>>(wkv_a_w, wkva, 576 * DIM_);
    cast_f32_bf16<<<2048, blk, 0, stream>>>(wo_w, wobf, DIM_ * DIM_);
    prep_wbnT<<<4096, blk, 0, stream>>>(wkv_b_w, wbnT);
    prep_wbv<<<4096, blk, 0, stream>>>(wkv_b_w, wbv);

    // --- q path ---
    gemm_bf16<<<dim3(12, 32, 1), blk, 0, stream>>>(x_bf, wqa, wq_a_b, q_a,
        M_TOT, QL_, DIM_, DIM_, DIM_, QL_, 0, 0, 0, 1.f, 0);
    rmsnorm_bf16<<<M_TOT, blk, 0, stream>>>(q_a, q_norm_w, QL_);
    gemm_bf16<<<dim3(24, 32, 1), blk, 0, stream>>>(q_a, wqb, wq_b_b, q,
        M_TOT, QSTR, QL_, QL_, QL_, QSTR, 0, 0, 0, 1.f, 0);
    rope_q<<<(M_TOT * NH_ * 32) / 256, blk, 0, stream>>>(q, freqs, QO);

    // --- kv path ---
    gemm_bf16<<<dim3(5, 32, 1), blk, 0, stream>>>(x_bf, wkva, wkv_a_b, kv_a,
        M_TOT, 576, DIM_, DIM_, DIM_, 576, 0, 0, 0, 1.f, 0);
    kv_norm_rope<<<M_TOT, blk, 0, stream>>>(kv_a, kv_norm_w, freqs, Kcat);
    transpose_kv<<<dim3(32, 8, 2), blk, 0, stream>>>(Kcat, KVT);

    // --- q absorb: QO[..., h, 0:512] = q_nope @ wkv_b[h,:128,:] ---
    gemm_bf16<<<dim3(4, 32, 16), blk, 0, stream>>>(q, wbnT, nullptr, QO,
        M_TOT, 512, 128, QSTR, 128, QOSTR, QKH_, 65536, 576, 1.f, 0);

    // --- fused flash attention (replaces scores+softmax+PV) ---
    mla_flash<<<dim3(32, 16, 2), blk, 0, stream>>>(QO, Kcat, KVT);

    // --- V projection: outh[m, h*128+d] = O[m,h,:] . wbv[h,d,:] ---
    gemm_bf16<<<dim3(1, 32, 16), blk, 0, stream>>>(QO, wbv, nullptr, outh,
        M_TOT, VH_, 512, QOSTR, 512, DIM_, 576, 65536, VH_, 1.f, 0);

    // --- output projection (fp32 out) ---
    gemm_bf16<<<dim3(16, 32, 1), blk, 0, stream>>>(outh, wobf, wo_b, out,
        M_TOT, DIM_, DIM_, DIM_, DIM_, DIM_, 0, 0, 0, 1.f, 1);
}